// Round 1
// baseline (270.962 us; speedup 1.0000x reference)
//
#include <hip/hip_runtime.h>
#include <hip/hip_bf16.h>

#define D 128
#define N_NODES 50000
#define N_EDGES 1600000
#define NCLS 21

// ws layout (bytes):
//   A      : 128 x 48 f32  (cols 0..23 = src proj folded w/ Wcls, 24..47 = dst; 21 real + 3 zero pad each)
//   bt     : 24 f32        (b_fuse @ Wcls + b_cls, padded)
//   Psrc   : N_NODES x 32 bf16 rows (64B-aligned rows -> 1 cacheline per gather)
//   Pdst   : N_NODES x 32 bf16
#define A_OFF    0
#define BT_OFF   (128*48*4)
#define PSRC_OFF 32768
#define PDST_OFF (PSRC_OFF + N_NODES*32*2)
// total ws need: PDST_OFF + N_NODES*32*2 = 6,432,768 bytes

// ---------------- K1: fold Wfuse @ Wcls -> A[128][48], b_total[24] ----------------
__global__ void ec_k1_fold(const float* __restrict__ Wsrc, const float* __restrict__ Wdst,
                           const float* __restrict__ Wcls, const float* __restrict__ bfuse,
                           const float* __restrict__ bcls, float* __restrict__ A,
                           float* __restrict__ bt) {
    int t = blockIdx.x * 256 + threadIdx.x;
    if (t < 128 * 48) {
        int k = t / 48, c48 = t % 48;
        int half = c48 / 24, c = c48 % 24;
        float v = 0.f;
        if (c < NCLS) {
            const float* W = half ? Wdst : Wsrc;
            const float* wrow = W + k * D;
#pragma unroll 4
            for (int j = 0; j < D; ++j) v += wrow[j] * Wcls[j * NCLS + c];
        }
        A[k * 48 + c48] = v;
    } else if (t < 128 * 48 + 24) {
        int c = t - 128 * 48;
        float v = 0.f;
        if (c < NCLS) {
            for (int j = 0; j < D; ++j) v += bfuse[j] * Wcls[j * NCLS + c];
            v += bcls[c];
        }
        bt[c] = v;
    }
}

// ---------------- K2: per-node projections P = emb @ A (+bt for src half) ----------------
// block = 256 threads handles 128 nodes.
// thread t: slot = t&63 -> nodes {base+slot, base+slot+64}; quarter = t>>6 -> 12 cols of 48.
// emb tile transposed into LDS [k][node] (stride 129 -> conflict-free b32 reads).
// A reads are wave-uniform (k uniform, quarter via readfirstlane) -> scalar-load friendly.
__global__ __launch_bounds__(256) void ec_k2_proj(const float* __restrict__ emb,
                                                  const float* __restrict__ A,
                                                  const float* __restrict__ bt,
                                                  __hip_bfloat16* __restrict__ Psrc,
                                                  __hip_bfloat16* __restrict__ Pdst) {
    __shared__ float et[128 * 129];  // [k][n], n in 0..127
    const int t = threadIdx.x;
    const int base = blockIdx.x * 128;

    // stage 128 rows x 128 floats, coalesced global float4, transposed LDS write
#pragma unroll
    for (int i = 0; i < 16; ++i) {
        int lin = t + i * 256;      // float4 slot 0..4095
        int n = lin >> 5;           // node row (32 float4 per row)
        int q = lin & 31;
        int gn = base + n;
        float4 v = make_float4(0.f, 0.f, 0.f, 0.f);
        if (gn < N_NODES) v = ((const float4*)(emb + (size_t)gn * D))[q];
        int k0 = q * 4;
        et[(k0 + 0) * 129 + n] = v.x;
        et[(k0 + 1) * 129 + n] = v.y;
        et[(k0 + 2) * 129 + n] = v.z;
        et[(k0 + 3) * 129 + n] = v.w;
    }
    __syncthreads();

    const int slot = t & 63;
    const int qb = __builtin_amdgcn_readfirstlane(t >> 6);  // 0..3, wave-uniform
    const float4* Aq = (const float4*)A + qb * 3;           // 12 cols = 3 float4 per 48-col row

    float acc0[12], acc1[12];
#pragma unroll
    for (int j = 0; j < 12; ++j) { acc0[j] = 0.f; acc1[j] = 0.f; }
    if (qb < 2) {
#pragma unroll
        for (int j = 0; j < 12; ++j) {
            float b = bt[qb * 12 + j];
            acc0[j] = b; acc1[j] = b;
        }
    }

    for (int k = 0; k < 128; ++k) {
        float e0 = et[k * 129 + slot];
        float e1 = et[k * 129 + slot + 64];
        float4 a0 = Aq[k * 12 + 0];
        float4 a1 = Aq[k * 12 + 1];
        float4 a2 = Aq[k * 12 + 2];
        acc0[0] += e0 * a0.x;  acc1[0] += e1 * a0.x;
        acc0[1] += e0 * a0.y;  acc1[1] += e1 * a0.y;
        acc0[2] += e0 * a0.z;  acc1[2] += e1 * a0.z;
        acc0[3] += e0 * a0.w;  acc1[3] += e1 * a0.w;
        acc0[4] += e0 * a1.x;  acc1[4] += e1 * a1.x;
        acc0[5] += e0 * a1.y;  acc1[5] += e1 * a1.y;
        acc0[6] += e0 * a1.z;  acc1[6] += e1 * a1.z;
        acc0[7] += e0 * a1.w;  acc1[7] += e1 * a1.w;
        acc0[8] += e0 * a2.x;  acc1[8] += e1 * a2.x;
        acc0[9] += e0 * a2.y;  acc1[9] += e1 * a2.y;
        acc0[10] += e0 * a2.z; acc1[10] += e1 * a2.z;
        acc0[11] += e0 * a2.w; acc1[11] += e1 * a2.w;
    }

    // epilogue: write 12 bf16 cols for each of the 2 nodes into Psrc or Pdst
    __hip_bfloat16* Pq = (qb < 2) ? Psrc : Pdst;
    const int coff = (qb & 1) * 12;  // col offset within 24-col payload (rows are 32 wide)
    int n0 = base + slot, n1 = base + slot + 64;
    if (n0 < N_NODES) {
        __hip_bfloat162* p = (__hip_bfloat162*)(Pq + (size_t)n0 * 32 + coff);
#pragma unroll
        for (int j = 0; j < 6; ++j) {
            __hip_bfloat162 h;
            h.x = __float2bfloat16(acc0[2 * j]);
            h.y = __float2bfloat16(acc0[2 * j + 1]);
            p[j] = h;
        }
    }
    if (n1 < N_NODES) {
        __hip_bfloat162* p = (__hip_bfloat162*)(Pq + (size_t)n1 * 32 + coff);
#pragma unroll
        for (int j = 0; j < 6; ++j) {
            __hip_bfloat162 h;
            h.x = __float2bfloat16(acc1[2 * j]);
            h.y = __float2bfloat16(acc1[2 * j + 1]);
            p[j] = h;
        }
    }
}

// ---------------- K3: per-edge gather + add ----------------
// thread per (edge, class): coalesced fp32 out writes; each gather row = one 64B line.
__global__ __launch_bounds__(256) void ec_k3_edges(const int* __restrict__ ei,
                                                   const __hip_bfloat16* __restrict__ Psrc,
                                                   const __hip_bfloat16* __restrict__ Pdst,
                                                   float* __restrict__ out) {
    int idx = blockIdx.x * 256 + threadIdx.x;
    if (idx >= N_EDGES * NCLS) return;
    int e = idx / NCLS;          // magic-mul div by 21
    int c = idx - e * NCLS;
    int s = ei[e];
    int d = ei[N_EDGES + e];
    float v = __bfloat162float(Psrc[(size_t)s * 32 + c]) +
              __bfloat162float(Pdst[(size_t)d * 32 + c]);
    out[idx] = v;
}

extern "C" void kernel_launch(void* const* d_in, const int* in_sizes, int n_in,
                              void* d_out, int out_size, void* d_ws, size_t ws_size,
                              hipStream_t stream) {
    const float* emb   = (const float*)d_in[0];
    const int*   ei    = (const int*)d_in[1];
    const float* Wsrc  = (const float*)d_in[2];
    const float* Wdst  = (const float*)d_in[3];
    const float* bfuse = (const float*)d_in[4];
    const float* Wcls  = (const float*)d_in[5];
    const float* bcls  = (const float*)d_in[6];
    float* out = (float*)d_out;

    char* ws = (char*)d_ws;
    float* A  = (float*)(ws + A_OFF);
    float* bt = (float*)(ws + BT_OFF);
    __hip_bfloat16* Psrc = (__hip_bfloat16*)(ws + PSRC_OFF);
    __hip_bfloat16* Pdst = (__hip_bfloat16*)(ws + PDST_OFF);

    // K1: fold weights (128*48 + 24 threads)
    ec_k1_fold<<<(128 * 48 + 24 + 255) / 256, 256, 0, stream>>>(Wsrc, Wdst, Wcls, bfuse, bcls, A, bt);

    // K2: node projections, 128 nodes/block
    ec_k2_proj<<<(N_NODES + 127) / 128, 256, 0, stream>>>(emb, A, bt, Psrc, Pdst);

    // K3: edge outputs
    int total = N_EDGES * NCLS;
    ec_k3_edges<<<(total + 255) / 256, 256, 0, stream>>>(ei, Psrc, Pdst, out);
}

// Round 3
// 227.333 us; speedup vs baseline: 1.1919x; 1.1919x over previous
//
#include <hip/hip_runtime.h>
#include <hip/hip_bf16.h>

#define D 128
#define N_NODES 50000
#define N_EDGES 1600000
#define NCLS 21

typedef float vfloat4 __attribute__((ext_vector_type(4)));  // clang-native for NT builtins

// ws layout (bytes):
//   A    : 128 x 48 f32   (cols 0..23 src-proj folded w/ Wcls, 24..47 dst; 21 real + 3 pad)
//   bt   : 24 f32         (b_fuse @ Wcls + b_cls, padded)
//   Psrc : N_NODES x 32 bf16 rows (64B rows -> 1 line per gather)
//   Pdst : N_NODES x 32 bf16
#define A_OFF    0
#define BT_OFF   (128*48*4)
#define PSRC_OFF 32768
#define PDST_OFF (PSRC_OFF + N_NODES*32*2)

// ---------------- K1: fold Wfuse @ Wcls -> A[128][48], b_total[24] ----------------
__global__ void ec_k1_fold(const float* __restrict__ Wsrc, const float* __restrict__ Wdst,
                           const float* __restrict__ Wcls, const float* __restrict__ bfuse,
                           const float* __restrict__ bcls, float* __restrict__ A,
                           float* __restrict__ bt) {
    int t = blockIdx.x * 256 + threadIdx.x;
    if (t < 128 * 48) {
        int k = t / 48, c48 = t % 48;
        int half = c48 / 24, c = c48 % 24;
        float v = 0.f;
        if (c < NCLS) {
            const float* W = half ? Wdst : Wsrc;
            const float* wrow = W + k * D;
#pragma unroll 4
            for (int j = 0; j < D; ++j) v += wrow[j] * Wcls[j * NCLS + c];
        }
        A[k * 48 + c48] = v;
    } else if (t < 128 * 48 + 24) {
        int c = t - 128 * 48;
        float v = 0.f;
        if (c < NCLS) {
            for (int j = 0; j < D; ++j) v += bfuse[j] * Wcls[j * NCLS + c];
            v += bcls[c];
        }
        bt[c] = v;
    }
}

// ---------------- K2: per-node projections P = emb @ A (+bt for src half) ----------------
// block=256 handles 128 nodes. k-tiled: stage 32 k-slices of emb transposed in LDS
// (et[kk][n], stride 130), A staged in LDS once (41 KB total LDS -> ~3 blocks/CU).
// thread t: slot=t&63 -> nodes {base+slot, base+slot+64}; qb=t>>6 -> 12 of 48 cols.
__global__ __launch_bounds__(256) void ec_k2_proj(const float* __restrict__ emb,
                                                  const float* __restrict__ A,
                                                  const float* __restrict__ bt,
                                                  __hip_bfloat16* __restrict__ Psrc,
                                                  __hip_bfloat16* __restrict__ Pdst) {
    __shared__ __align__(16) float As[128 * 48];   // 24576 B
    __shared__ __align__(16) float et[32 * 130];   // 16640 B
    const int t = threadIdx.x;
    const int base = blockIdx.x * 128;

    // stage A: 1536 float4, 6 per thread, coalesced
#pragma unroll
    for (int i = 0; i < 6; ++i) {
        int s4 = t + i * 256;
        ((float4*)As)[s4] = ((const float4*)A)[s4];
    }

    const int slot = t & 63;
    const int qb = __builtin_amdgcn_readfirstlane(t >> 6);  // 0..3 wave-uniform
    const float4* Aq4 = ((const float4*)As) + qb * 3;

    float acc0[12], acc1[12];
#pragma unroll
    for (int j = 0; j < 12; ++j) { acc0[j] = 0.f; acc1[j] = 0.f; }
    if (qb < 2) {
#pragma unroll
        for (int j = 0; j < 12; ++j) {
            float b = bt[qb * 12 + j];
            acc0[j] = b; acc1[j] = b;
        }
    }

    for (int kt = 0; kt < 4; ++kt) {
        __syncthreads();
        // stage 128 nodes x 32 k (transposed): 1024 float4, 4 per thread
#pragma unroll
        for (int i = 0; i < 4; ++i) {
            int lin = t + i * 256;
            int n = lin >> 3, q = lin & 7;
            int gn = base + n;
            float4 v = make_float4(0.f, 0.f, 0.f, 0.f);
            if (gn < N_NODES) v = ((const float4*)(emb + (size_t)gn * D + kt * 32))[q];
            int k0 = q * 4;
            et[(k0 + 0) * 130 + n] = v.x;
            et[(k0 + 1) * 130 + n] = v.y;
            et[(k0 + 2) * 130 + n] = v.z;
            et[(k0 + 3) * 130 + n] = v.w;
        }
        __syncthreads();

#pragma unroll
        for (int kk = 0; kk < 32; ++kk) {
            int k = kt * 32 + kk;
            float e0 = et[kk * 130 + slot];
            float e1 = et[kk * 130 + slot + 64];
            float4 a0 = Aq4[k * 12 + 0];
            float4 a1 = Aq4[k * 12 + 1];
            float4 a2 = Aq4[k * 12 + 2];
            acc0[0]  += e0 * a0.x;  acc1[0]  += e1 * a0.x;
            acc0[1]  += e0 * a0.y;  acc1[1]  += e1 * a0.y;
            acc0[2]  += e0 * a0.z;  acc1[2]  += e1 * a0.z;
            acc0[3]  += e0 * a0.w;  acc1[3]  += e1 * a0.w;
            acc0[4]  += e0 * a1.x;  acc1[4]  += e1 * a1.x;
            acc0[5]  += e0 * a1.y;  acc1[5]  += e1 * a1.y;
            acc0[6]  += e0 * a1.z;  acc1[6]  += e1 * a1.z;
            acc0[7]  += e0 * a1.w;  acc1[7]  += e1 * a1.w;
            acc0[8]  += e0 * a2.x;  acc1[8]  += e1 * a2.x;
            acc0[9]  += e0 * a2.y;  acc1[9]  += e1 * a2.y;
            acc0[10] += e0 * a2.z;  acc1[10] += e1 * a2.z;
            acc0[11] += e0 * a2.w;  acc1[11] += e1 * a2.w;
        }
    }

    __hip_bfloat16* Pq = (qb < 2) ? Psrc : Pdst;
    const int coff = (qb & 1) * 12;
    int n0 = base + slot, n1 = base + slot + 64;
    if (n0 < N_NODES) {
        __hip_bfloat162* p = (__hip_bfloat162*)(Pq + (size_t)n0 * 32 + coff);
#pragma unroll
        for (int j = 0; j < 6; ++j) {
            __hip_bfloat162 h;
            h.x = __float2bfloat16(acc0[2 * j]);
            h.y = __float2bfloat16(acc0[2 * j + 1]);
            p[j] = h;
        }
    }
    if (n1 < N_NODES) {
        __hip_bfloat162* p = (__hip_bfloat162*)(Pq + (size_t)n1 * 32 + coff);
#pragma unroll
        for (int j = 0; j < 6; ++j) {
            __hip_bfloat162 h;
            h.x = __float2bfloat16(acc1[2 * j]);
            h.y = __float2bfloat16(acc1[2 * j + 1]);
            p[j] = h;
        }
    }
}

// ---------------- K3: per-edge gather + add, edge-centric ----------------
// block=256 handles 512 edges (2/thread). Gather full P rows (1-2 lines each),
// fp32 add, stage 21 floats/edge in LDS (stride 21 words -> conflict-free),
// then coalesced float4 NT stores (don't evict P-tables from L2).
#define EPB 512
__device__ __forceinline__ float bf_lo(unsigned u) { return __uint_as_float(u << 16); }
__device__ __forceinline__ float bf_hi(unsigned u) { return __uint_as_float(u & 0xFFFF0000u); }

__global__ __launch_bounds__(256) void ec_k3_edges(const int* __restrict__ ei,
                                                   const __hip_bfloat16* __restrict__ Psrc,
                                                   const __hip_bfloat16* __restrict__ Pdst,
                                                   float* __restrict__ out) {
    __shared__ __align__(16) float sm[EPB * NCLS];  // 43008 B
    const int t = threadIdx.x;
    const int e0 = blockIdx.x * EPB;  // grid exactly covers N_EDGES (512*3125)

    int s[2], d[2];
#pragma unroll
    for (int j = 0; j < 2; ++j) {
        int e = e0 + t + j * 256;
        s[j] = __builtin_nontemporal_load(ei + e);
        d[j] = __builtin_nontemporal_load(ei + N_EDGES + e);
    }

#pragma unroll
    for (int j = 0; j < 2; ++j) {
        const uint4* ps = (const uint4*)(Psrc + (size_t)s[j] * 32);
        const uint4* pd = (const uint4*)(Pdst + (size_t)d[j] * 32);
        uint4 a0 = ps[0], a1 = ps[1];            // c0..15
        uint4 b0 = pd[0], b1 = pd[1];
        unsigned a2 = ((const unsigned*)(ps + 2))[0];  // c16..17
        unsigned a3 = ((const unsigned*)(ps + 2))[1];  // c18..19
        unsigned a4 = ((const unsigned*)(ps + 2))[2];  // c20
        unsigned b2 = ((const unsigned*)(pd + 2))[0];
        unsigned b3 = ((const unsigned*)(pd + 2))[1];
        unsigned b4 = ((const unsigned*)(pd + 2))[2];

        float v[NCLS];
        v[0]  = bf_lo(a0.x) + bf_lo(b0.x);  v[1]  = bf_hi(a0.x) + bf_hi(b0.x);
        v[2]  = bf_lo(a0.y) + bf_lo(b0.y);  v[3]  = bf_hi(a0.y) + bf_hi(b0.y);
        v[4]  = bf_lo(a0.z) + bf_lo(b0.z);  v[5]  = bf_hi(a0.z) + bf_hi(b0.z);
        v[6]  = bf_lo(a0.w) + bf_lo(b0.w);  v[7]  = bf_hi(a0.w) + bf_hi(b0.w);
        v[8]  = bf_lo(a1.x) + bf_lo(b1.x);  v[9]  = bf_hi(a1.x) + bf_hi(b1.x);
        v[10] = bf_lo(a1.y) + bf_lo(b1.y);  v[11] = bf_hi(a1.y) + bf_hi(b1.y);
        v[12] = bf_lo(a1.z) + bf_lo(b1.z);  v[13] = bf_hi(a1.z) + bf_hi(b1.z);
        v[14] = bf_lo(a1.w) + bf_lo(b1.w);  v[15] = bf_hi(a1.w) + bf_hi(b1.w);
        v[16] = bf_lo(a2)   + bf_lo(b2);    v[17] = bf_hi(a2)   + bf_hi(b2);
        v[18] = bf_lo(a3)   + bf_lo(b3);    v[19] = bf_hi(a3)   + bf_hi(b3);
        v[20] = bf_lo(a4)   + bf_lo(b4);

        int el = t + j * 256;
        float* row = sm + el * NCLS;  // stride 21 words: coprime w/ 32 banks
#pragma unroll
        for (int c = 0; c < NCLS; ++c) row[c] = v[c];
    }
    __syncthreads();

    // coalesced NT float4 stores: EPB*21/4 = 2688 float4 per block
    const vfloat4* sm4 = (const vfloat4*)sm;
    vfloat4* o4 = (vfloat4*)(out + (size_t)e0 * NCLS);
    for (int i = t; i < EPB * NCLS / 4; i += 256)
        __builtin_nontemporal_store(sm4[i], o4 + i);
}

extern "C" void kernel_launch(void* const* d_in, const int* in_sizes, int n_in,
                              void* d_out, int out_size, void* d_ws, size_t ws_size,
                              hipStream_t stream) {
    const float* emb   = (const float*)d_in[0];
    const int*   ei    = (const int*)d_in[1];
    const float* Wsrc  = (const float*)d_in[2];
    const float* Wdst  = (const float*)d_in[3];
    const float* bfuse = (const float*)d_in[4];
    const float* Wcls  = (const float*)d_in[5];
    const float* bcls  = (const float*)d_in[6];
    float* out = (float*)d_out;

    char* ws = (char*)d_ws;
    float* A  = (float*)(ws + A_OFF);
    float* bt = (float*)(ws + BT_OFF);
    __hip_bfloat16* Psrc = (__hip_bfloat16*)(ws + PSRC_OFF);
    __hip_bfloat16* Pdst = (__hip_bfloat16*)(ws + PDST_OFF);

    ec_k1_fold<<<(128 * 48 + 24 + 255) / 256, 256, 0, stream>>>(Wsrc, Wdst, Wcls, bfuse, bcls, A, bt);
    ec_k2_proj<<<(N_NODES + 127) / 128, 256, 0, stream>>>(emb, A, bt, Psrc, Pdst);
    ec_k3_edges<<<N_EDGES / EPB, 256, 0, stream>>>(ei, Psrc, Pdst, out);
}